// Round 13
// baseline (1258.074 us; speedup 1.0000x reference)
//
#include <hip/hip_runtime.h>
#include <stdint.h>

#define B_ 16
#define N_ 4096
#define NPOINT_ 1024
#define NSAMPLE_ 32
#define PPB 32768            // NPOINT_*NSAMPLE_
#define PTOT 524288          // B_*PPB
#define EPS_ 1e-5f

typedef float v2f __attribute__((ext_vector_type(2)));
typedef __attribute__((ext_vector_type(8))) short bf16x8;
typedef __attribute__((ext_vector_type(4))) float f32x4;

// ---------- bf16 helpers ----------
__device__ __forceinline__ float bf2f(unsigned short h) {
    unsigned int u = ((unsigned int)h) << 16;
    float f; __builtin_memcpy(&f, &u, 4); return f;
}
__device__ __forceinline__ unsigned short f2bf(float f) {
    unsigned int u; __builtin_memcpy(&u, &f, 4);
    u = (u + 0x7fffu + ((u >> 16) & 1u)) >> 16;   // RNE
    return (unsigned short)u;
}

// ---------- prep: zero G3/s3/G1/s1, cast w1,w2 -> bf16 ----------
__global__ __launch_bounds__(256) void prep_kernel(const float* __restrict__ w1,
                                                   const float* __restrict__ w2,
                                                   unsigned short* __restrict__ w1bf,
                                                   unsigned short* __restrict__ w2bf,
                                                   float* __restrict__ g3s3) {
    int i = blockIdx.x * 256 + threadIdx.x;   // 32 blocks -> 8192
    if (i < 4187) g3s3[i] = 0.f;
    if (i < 4096) w1bf[i] = f2bf(w1[i]);
    if (i < 8192) w2bf[i] = f2bf(w2[i]);
}

// ---------- FPS ----------
// R27: 16 waves (1024 thr) per batch = 4 waves/SIMD. Per-SIMD issue is
// invariant (4096 point-updates on 4 SIMDs) but the serial latency segments
// (DPP chain, barrier drain, key-tree read, center gather ~600 cyc/iter) are
// hidden by co-resident waves' issue — 4 streams/SIMD vs 2 (R17's 1->2 gave
// -40 us). Per-wave dist phase halves (4 pts/thread, 2 v2f pairs). Tree over
// 16 keys (depth 4). Tie-break unchanged: slot s = tid + s*1024 ascending,
// ballots in slot order, ctz lane, (Mw,~bi) key -> selection bit-identical.
#define DPP_U32_MAX(ctrl)                                                          \
    {                                                                              \
        unsigned int n = (unsigned int)__builtin_amdgcn_update_dpp(                \
            (int)mb, (int)mb, ctrl, 0xF, 0xF, false);                              \
        mb = (n > mb) ? n : mb;                                                    \
    }

__global__ __launch_bounds__(1024) void fps_kernel(const float* __restrict__ xyz,
                                                   float* __restrict__ out0) {
    const int b = blockIdx.x;
    const int tid = threadIdx.x;                 // 0..1023
    const int lane = tid & 63, wid = tid >> 6;   // wid 0..15
    __shared__ float sx[N_], sy[N_], sz[N_];
    __shared__ __align__(16) unsigned long long red[2][16];
    __shared__ int sidx[NPOINT_];
    const float* xb = xyz + (size_t)b * 3 * N_;
    for (int p = tid; p < N_; p += 1024) {
        sx[p] = xb[p]; sy[p] = xb[N_ + p]; sz[p] = xb[2 * N_ + p];
    }
    __syncthreads();
    // slot s = j*2+k covers point index tid + s*1024 (ascending in s)
    v2f px2[2], py2[2], pz2[2], md2[2];
#pragma unroll
    for (int j = 0; j < 2; ++j) {
        int p = tid + j * 2048;
        px2[j][0] = sx[p];       px2[j][1] = sx[p + 1024];
        py2[j][0] = sy[p];       py2[j][1] = sy[p + 1024];
        pz2[j][0] = sz[p];       pz2[j][1] = sz[p + 1024];
        md2[j][0] = 1e10f;       md2[j][1] = 1e10f;
    }
    int cur = 0;
    for (int t = 0; t < NPOINT_; ++t) {
        if (tid == 0) sidx[t] = cur;           // LDS only — no vmcnt on the loop
        float cx = sx[cur], cy = sy[cur], cz = sz[cur];
        v2f c2x; c2x[0] = cx; c2x[1] = cx;
        v2f c2y; c2y[0] = cy; c2y[1] = cy;
        v2f c2z; c2z[0] = cz; c2z[1] = cz;
#pragma unroll
        for (int j = 0; j < 2; ++j) {
            // pk sub/mul/fma/min: per-element rounding identical to the
            // scalar __fmul_rn/__builtin_fmaf chain -> same selection
            v2f dx = px2[j] - c2x;
            v2f dy = py2[j] - c2y;
            v2f dz = pz2[j] - c2z;
            v2f t0 = dx * dx;
            v2f t1 = __builtin_elementwise_fma(dy, dy, t0);
            v2f d2 = __builtin_elementwise_fma(dz, dz, t1);
            md2[j] = __builtin_elementwise_min(md2[j], d2);
        }
        // lane-local max of the 4 running minima (value only)
        v2f m01 = __builtin_elementwise_max(md2[0], md2[1]);
        float lm = fmaxf(m01[0], m01[1]);
        unsigned int mb; __builtin_memcpy(&mb, &lm, 4);   // >=0 -> monotone bits
        DPP_U32_MAX(0x111)   // row_shr:1
        DPP_U32_MAX(0x112)   // row_shr:2
        DPP_U32_MAX(0x114)   // row_shr:4
        DPP_U32_MAX(0x118)   // row_shr:8
        DPP_U32_MAX(0x142)   // row_bcast:15
        DPP_U32_MAX(0x143)   // row_bcast:31
        unsigned int Mw = (unsigned int)__builtin_amdgcn_readlane((int)mb, 63);
        // equality ballots in slot order; results are wave-uniform (SGPR)
        unsigned long long bm[4];
#pragma unroll
        for (int j = 0; j < 2; ++j) {
#pragma unroll
            for (int k = 0; k < 2; ++k) {
                float f = md2[j][k];
                unsigned int v; __builtin_memcpy(&v, &f, 4);
                bm[j * 2 + k] = __ballot(v == Mw);
            }
        }
        // first nonzero slot (ascending) + lowest lane = smallest index among
        // ties; pure SALU select chain (uniform values)
        int off = 0; unsigned long long sel = 0;
#pragma unroll
        for (int s = 3; s >= 0; --s)
            if (bm[s] != 0ull) { sel = bm[s]; off = s; }
        int bi = off * 1024 + wid * 64 + (int)__builtin_ctzll(sel);
        unsigned long long key =
            ((unsigned long long)Mw << 32) | (unsigned int)~bi;
        if (lane == 0) red[t & 1][wid] = key;   // key is wave-uniform
        __syncthreads();
        // max tree over 16 per-wave keys (no cross-wave ties: disjoint idx sets)
        const ulonglong2* rp = (const ulonglong2*)&red[t & 1][0];
        ulonglong2 r0 = rp[0], r1 = rp[1], r2 = rp[2], r3 = rp[3];
        ulonglong2 r4 = rp[4], r5 = rp[5], r6 = rp[6], r7 = rp[7];
        unsigned long long a0 = (r0.x > r0.y) ? r0.x : r0.y;
        unsigned long long a1 = (r1.x > r1.y) ? r1.x : r1.y;
        unsigned long long a2 = (r2.x > r2.y) ? r2.x : r2.y;
        unsigned long long a3 = (r3.x > r3.y) ? r3.x : r3.y;
        unsigned long long a4 = (r4.x > r4.y) ? r4.x : r4.y;
        unsigned long long a5 = (r5.x > r5.y) ? r5.x : r5.y;
        unsigned long long a6 = (r6.x > r6.y) ? r6.x : r6.y;
        unsigned long long a7 = (r7.x > r7.y) ? r7.x : r7.y;
        unsigned long long b0 = (a0 > a1) ? a0 : a1;
        unsigned long long b1 = (a2 > a3) ? a2 : a3;
        unsigned long long b2 = (a4 > a5) ? a4 : a5;
        unsigned long long b3 = (a6 > a7) ? a6 : a7;
        unsigned long long c0 = (b0 > b1) ? b0 : b1;
        unsigned long long c1 = (b2 > b3) ? b2 : b3;
        unsigned long long mm = (c0 > c1) ? c0 : c1;
        cur = (int)(~(unsigned int)mm) & (N_ - 1);
    }
    __syncthreads();
    // coalesced epilogue: gather centers from LDS, store once
    for (int t = tid; t < NPOINT_; t += 1024) {
        int ix = sidx[t];
        out0[(size_t)b * 3 * NPOINT_ + t]               = sx[ix];
        out0[(size_t)b * 3 * NPOINT_ + NPOINT_ + t]     = sy[ix];
        out0[(size_t)b * 3 * NPOINT_ + 2 * NPOINT_ + t] = sz[ix];
    }
}

// ---------- ball query (R26: 2 queries per wave — share the point stream) ----------
__global__ __launch_bounds__(256) void ball_kernel(const float* __restrict__ xyz,
                                                   const float* __restrict__ out0,
                                                   int* __restrict__ ball_idx) {
    int gid  = (blockIdx.x * 256 + threadIdx.x) >> 6;   // 2048 blocks -> 8192 gids
    int lane = threadIdx.x & 63;
    int b = gid >> 9, s0 = (gid & 511) * 2;
    const float* xb = xyz + (size_t)b * 3 * N_;
    float q0x = out0[(size_t)b * 3 * NPOINT_ + s0];
    float q0y = out0[(size_t)b * 3 * NPOINT_ + NPOINT_ + s0];
    float q0z = out0[(size_t)b * 3 * NPOINT_ + 2 * NPOINT_ + s0];
    float q1x = out0[(size_t)b * 3 * NPOINT_ + s0 + 1];
    float q1y = out0[(size_t)b * 3 * NPOINT_ + NPOINT_ + s0 + 1];
    float q1z = out0[(size_t)b * 3 * NPOINT_ + 2 * NPOINT_ + s0 + 1];
    float qs0 = __builtin_fmaf(q0z, q0z, __builtin_fmaf(q0y, q0y, __fmul_rn(q0x, q0x)));
    float qs1 = __builtin_fmaf(q1z, q1z, __builtin_fmaf(q1y, q1y, __fmul_rn(q1x, q1x)));
    int cnt0 = 0, first0 = 0, cnt1 = 0, first1 = 0;
    int* outp0 = ball_idx + ((size_t)b * NPOINT_ + s0) * NSAMPLE_;
    int* outp1 = outp0 + NSAMPLE_;
#pragma unroll 2
    for (int n0 = 0; n0 < N_; n0 += 64) {
        int n = n0 + lane;
        float px = xb[n], py = xb[N_ + n], pz = xb[2 * N_ + n];
        float ps  = __builtin_fmaf(pz, pz, __builtin_fmaf(py, py, __fmul_rn(px, px)));
        float dot0 = __builtin_fmaf(q0z, pz, __builtin_fmaf(q0y, py, __fmul_rn(q0x, px)));
        float d0   = __fadd_rn(__builtin_fmaf(-2.f, dot0, qs0), ps);
        float dot1 = __builtin_fmaf(q1z, pz, __builtin_fmaf(q1y, py, __fmul_rn(q1x, px)));
        float d1   = __fadd_rn(__builtin_fmaf(-2.f, dot1, qs1), ps);
        bool ok0 = !(d0 > 0.04f);
        bool ok1 = !(d1 > 0.04f);
        unsigned long long m0 = __ballot(ok0);
        unsigned long long m1 = __ballot(ok1);
        if (m0) {
            if (cnt0 == 0) first0 = n0 + (__ffsll((unsigned long long)m0) - 1);
            if (ok0) {
                int r = __popcll(m0 & ((1ull << lane) - 1ull));
                int pos = cnt0 + r;
                if (pos < NSAMPLE_) outp0[pos] = n;
            }
            cnt0 += __popcll(m0);
        }
        if (m1) {
            if (cnt1 == 0) first1 = n0 + (__ffsll((unsigned long long)m1) - 1);
            if (ok1) {
                int r = __popcll(m1 & ((1ull << lane) - 1ull));
                int pos = cnt1 + r;
                if (pos < NSAMPLE_) outp1[pos] = n;
            }
            cnt1 += __popcll(m1);
        }
    }
    if (cnt0 < NSAMPLE_) {
        for (int pos = cnt0 + lane; pos < NSAMPLE_; pos += 64) outp0[pos] = first0;
    }
    if (cnt1 < NSAMPLE_) {
        for (int pos = cnt1 + lane; pos < NSAMPLE_; pos += 64) outp1[pos] = first1;
    }
}

// ---------- gram1: G1 = sum x x^T (6x6 upper tri, 21) + s1 = sum x (6) ----------
__global__ __launch_bounds__(256) void gram1_kernel(const float* __restrict__ xyz,
                                                    const float* __restrict__ pts,
                                                    const float* __restrict__ out0,
                                                    const int* __restrict__ ball_idx,
                                                    float* __restrict__ g1s1) {
    __shared__ float red[4][27];
    int tid = threadIdx.x;
    int lane = tid & 63, w = tid >> 6;
    float a[27];
#pragma unroll
    for (int i = 0; i < 27; ++i) a[i] = 0.f;
    for (int k = 0; k < 4; ++k) {
        int p = blockIdx.x * 1024 + k * 256 + tid;
        int b = p >> 15, s = (p & 32767) >> 5;
        int gi = ball_idx[p];
        const float* xb = xyz + (size_t)b * 3 * N_;
        const float* pb = pts + (size_t)b * 3 * N_;
        float x[6];
        x[0] = xb[gi]          - out0[(size_t)b * 3 * NPOINT_ + s];
        x[1] = xb[N_ + gi]     - out0[(size_t)b * 3 * NPOINT_ + NPOINT_ + s];
        x[2] = xb[2 * N_ + gi] - out0[(size_t)b * 3 * NPOINT_ + 2 * NPOINT_ + s];
        x[3] = pb[gi]; x[4] = pb[N_ + gi]; x[5] = pb[2 * N_ + gi];
        int idx = 0;
#pragma unroll
        for (int i = 0; i < 6; ++i)
#pragma unroll
            for (int j = i; j < 6; ++j) {
                a[idx] = __builtin_fmaf(x[i], x[j], a[idx]);
                ++idx;
            }
#pragma unroll
        for (int i = 0; i < 6; ++i) a[21 + i] += x[i];
    }
#pragma unroll
    for (int i = 0; i < 27; ++i) {
#pragma unroll
        for (int off = 32; off >= 1; off >>= 1)
            a[i] += __shfl_down(a[i], off);
    }
    if (lane == 0) {
#pragma unroll
        for (int i = 0; i < 27; ++i) red[w][i] = a[i];
    }
    __syncthreads();
    if (tid < 27)
        atomicAdd(&g1s1[tid], red[0][tid] + red[1][tid] + red[2][tid] + red[3][tid]);
}

// ---------- finalize1: G1/s1 -> scale1/shift1 (double, finalize3 pattern) ----------
__global__ __launch_bounds__(64) void finalize1_kernel(const float* __restrict__ g1s1,
                                                       const float* __restrict__ w0,
                                                       const float* __restrict__ b0,
                                                       const float* __restrict__ gamma,
                                                       const float* __restrict__ beta,
                                                       float* __restrict__ scale,
                                                       float* __restrict__ shift) {
    int o = threadIdx.x;
    const float* wr = w0 + o * 6;
    double G[6][6];
    {
        int idx = 0;
        for (int i = 0; i < 6; ++i)
            for (int j = i; j < 6; ++j) { G[i][j] = G[j][i] = (double)g1s1[idx]; ++idx; }
    }
    double ws = 0.0;
    for (int c = 0; c < 6; ++c) ws += (double)wr[c] * (double)g1s1[21 + c];
    double qf = 0.0;
    for (int i = 0; i < 6; ++i) {
        double ti = 0.0;
        for (int j = 0; j < 6; ++j) ti += G[i][j] * (double)wr[j];
        qf += (double)wr[i] * ti;
    }
    const double invP = 1.0 / (double)PTOT;
    double bb = (double)b0[o];
    double mean = ws * invP + bb;
    double ey2 = qf * invP + 2.0 * bb * (ws * invP) + bb * bb;
    double var = ey2 - mean * mean;
    float sc = gamma[o] / sqrtf((float)var + EPS_);
    scale[o] = sc;
    shift[o] = beta[o] - (float)mean * sc;
}

// ---------- reduce partials -> scale/shift (used for layer 2) ----------
__global__ __launch_bounds__(256) void reduce_finalize_kernel(const float* __restrict__ partials,
                                                              int nblocks,
                                                              const float* __restrict__ gamma,
                                                              const float* __restrict__ beta,
                                                              float* __restrict__ scale,
                                                              float* __restrict__ shift) {
    int c = blockIdx.x;
    int tid = threadIdx.x, lane = tid & 63, wid = tid >> 6;
    float s1 = 0.f, s2 = 0.f;
    for (int i = tid; i < nblocks; i += 256) {
        s1 += partials[(size_t)i * 128 + c];
        s2 += partials[(size_t)i * 128 + 64 + c];
    }
#pragma unroll
    for (int off = 32; off >= 1; off >>= 1) {
        s1 += __shfl_down(s1, off);
        s2 += __shfl_down(s2, off);
    }
    __shared__ float r1[4], r2[4];
    if (lane == 0) { r1[wid] = s1; r2[wid] = s2; }
    __syncthreads();
    if (tid == 0) {
        float S1 = r1[0] + r1[1] + r1[2] + r1[3];
        float S2 = r2[0] + r2[1] + r2[2] + r2[3];
        const float inv = 1.f / (float)PTOT;
        float m = S1 * inv;
        float v = S2 * inv - m * m;
        float sc = gamma[c] / sqrtf(v + EPS_);
        scale[c] = sc;
        shift[c] = beta[c] - m * sc;
    }
}

// ---------- conv2 (R24 MFMA; R25 staging spread — kept) ----------
#define XT_S 72
__global__ __launch_bounds__(256) void conv2_mfma_kernel(const float* __restrict__ xyz,
                                                         const float* __restrict__ pts,
                                                         const float* __restrict__ out0,
                                                         const int* __restrict__ ball_idx,
                                                         const float* __restrict__ w0,
                                                         const float* __restrict__ b0,
                                                         const unsigned short* __restrict__ w1bf,
                                                         const float* __restrict__ b1,
                                                         const float* __restrict__ scale1,
                                                         const float* __restrict__ shift1,
                                                         unsigned short* __restrict__ y2,
                                                         float* __restrict__ partial2) {
    __shared__ float sw0[448];
    __shared__ float x1s[6 * 64];
    __shared__ __align__(16) unsigned short Xt[64 * XT_S];   // [p][c] bf16
    __shared__ float ssc[64], ssh[64], sb1[64];
    __shared__ float lsum[2][64], lsq[2][64];
    int tid = threadIdx.x;
    int lane = tid & 63, w = tid >> 6;
    int p0 = blockIdx.x * 64;
    for (int i = tid; i < 448; i += 256) sw0[i] = (i < 384) ? w0[i] : b0[i - 384];
    if (tid < 64) { ssc[tid] = scale1[tid]; ssh[tid] = shift1[tid]; sb1[tid] = b1[tid]; }
    // 384 gather items spread over 256 threads
    for (int it = tid; it < 384; it += 256) {
        int ch = it >> 6, p = it & 63;
        int pp = p0 + p;
        int b = pp >> 15, s = (pp & 32767) >> 5;
        int gi = ball_idx[pp];
        float v;
        if (ch < 3)
            v = xyz[(size_t)b * 3 * N_ + (size_t)ch * N_ + gi]
              - out0[(size_t)b * 3 * NPOINT_ + (size_t)ch * NPOINT_ + s];
        else
            v = pts[(size_t)b * 3 * N_ + (size_t)(ch - 3) * N_ + gi];
        x1s[ch * 64 + p] = v;
    }
    // A-frags (weights) from global while x1s staging settles
    int o0 = (w >> 1) * 32, pq0 = (w & 1) * 32;
    bf16x8 afrag[2][2];
#pragma unroll
    for (int ot = 0; ot < 2; ++ot)
#pragma unroll
        for (int k = 0; k < 2; ++k)
            afrag[ot][k] = *(const bf16x8*)(w1bf +
                (size_t)(o0 + ot * 16 + (lane & 15)) * 64 + k * 32 + (lane >> 4) * 8);
    __syncthreads();
    // stage 1: thread -> point p=lane, channels cb..cb+15 (K=6 VALU GEMM)
    {
        int p = lane, cb = w * 16;
        float v0 = x1s[p], v1 = x1s[64 + p], v2 = x1s[128 + p];
        float v3 = x1s[192 + p], v4 = x1s[256 + p], v5 = x1s[320 + p];
        unsigned short row[16];
#pragma unroll
        for (int j = 0; j < 16; ++j) {
            int c = cb + j;
            float a = sw0[384 + c];
            a += sw0[c * 6 + 0] * v0; a += sw0[c * 6 + 1] * v1; a += sw0[c * 6 + 2] * v2;
            a += sw0[c * 6 + 3] * v3; a += sw0[c * 6 + 4] * v4; a += sw0[c * 6 + 5] * v5;
            row[j] = f2bf(fmaxf(a * ssc[c] + ssh[c], 0.f));
        }
#pragma unroll
        for (int qq = 0; qq < 4; ++qq) {
            ushort4 u = make_ushort4(row[4 * qq], row[4 * qq + 1],
                                     row[4 * qq + 2], row[4 * qq + 3]);
            *(ushort4*)&Xt[p * XT_S + cb + 4 * qq] = u;
        }
    }
    __syncthreads();
    // B-frags from LDS
    bf16x8 bfrag[2][2];
#pragma unroll
    for (int pt = 0; pt < 2; ++pt)
#pragma unroll
        for (int k = 0; k < 2; ++k)
            bfrag[pt][k] = *(const bf16x8*)&Xt[
                (pq0 + pt * 16 + (lane & 15)) * XT_S + k * 32 + (lane >> 4) * 8];
    // MFMA: D[o][p]
    f32x4 acc[2][2];
#pragma unroll
    for (int ot = 0; ot < 2; ++ot)
#pragma unroll
        for (int pt = 0; pt < 2; ++pt) {
            f32x4 a = {0.f, 0.f, 0.f, 0.f};
            a = __builtin_amdgcn_mfma_f32_16x16x32_bf16(afrag[ot][0], bfrag[pt][0], a, 0, 0, 0);
            a = __builtin_amdgcn_mfma_f32_16x16x32_bf16(afrag[ot][1], bfrag[pt][1], a, 0, 0, 0);
            acc[ot][pt] = a;
        }
    // epilogue: +b1, y2 store (bf16), stats over p
#pragma unroll
    for (int ot = 0; ot < 2; ++ot) {
        float sA[4] = {0.f, 0.f, 0.f, 0.f}, sQ[4] = {0.f, 0.f, 0.f, 0.f};
#pragma unroll
        for (int pt = 0; pt < 2; ++pt) {
            int p = pq0 + pt * 16 + (lane & 15);
#pragma unroll
            for (int r = 0; r < 4; ++r) {
                int o = o0 + ot * 16 + (lane >> 4) * 4 + r;
                float val = acc[ot][pt][r] + sb1[o];
                y2[(size_t)o * PTOT + p0 + p] = f2bf(val);
                sA[r] += val;
                sQ[r] = __builtin_fmaf(val, val, sQ[r]);
            }
        }
#pragma unroll
        for (int off2 = 8; off2 >= 1; off2 >>= 1)
#pragma unroll
            for (int r = 0; r < 4; ++r) {
                sA[r] += __shfl_down(sA[r], off2);
                sQ[r] += __shfl_down(sQ[r], off2);
            }
        if ((lane & 15) == 0) {
#pragma unroll
            for (int r = 0; r < 4; ++r) {
                int o = o0 + ot * 16 + (lane >> 4) * 4 + r;
                lsum[w & 1][o] = sA[r];
                lsq[w & 1][o] = sQ[r];
            }
        }
    }
    __syncthreads();
    if (tid < 64)
        partial2[(size_t)blockIdx.x * 128 + tid] = lsum[0][tid] + lsum[1][tid];
    else if (tid < 128)
        partial2[(size_t)blockIdx.x * 128 + tid] = lsq[0][tid - 64] + lsq[1][tid - 64];
}

// ---------- gram3 (R23: MFMA, no LDS staging — verified) ----------
__global__ __launch_bounds__(256) void gram3_mfma_kernel(const unsigned short* __restrict__ y2,
                                                         const float* __restrict__ scale2,
                                                         const float* __restrict__ shift2,
                                                         float* __restrict__ G3,
                                                         float* __restrict__ s3) {
    __shared__ float g3loc[4096];
    __shared__ float s3loc[64];
    int tid = threadIdx.x;
    int lane = tid & 63, w = tid >> 6;
    for (int i = tid; i < 4096; i += 256) g3loc[i] = 0.f;
    if (tid < 64) s3loc[tid] = 0.f;
    float sc[4], sh[4];
#pragma unroll
    for (int ct = 0; ct < 4; ++ct) {
        int c = ct * 16 + (lane & 15);
        sc[ct] = scale2[c]; sh[ct] = shift2[c];
    }
    f32x4 acc[4][4];
#pragma unroll
    for (int i = 0; i < 4; ++i)
#pragma unroll
        for (int j = 0; j < 4; ++j) acc[i][j] = (f32x4){0.f, 0.f, 0.f, 0.f};
    float rs[4] = {0.f, 0.f, 0.f, 0.f};
    int pw0 = blockIdx.x * 1024 + w * 256;   // wave: 256 points = 8 chunks of 32
    for (int chk = 0; chk < 8; ++chk) {
        int pb = pw0 + chk * 32 + (lane >> 4) * 8;
        bf16x8 frag[4];
#pragma unroll
        for (int ct = 0; ct < 4; ++ct) {
            int c = ct * 16 + (lane & 15);
            ushort4 u0 = *(const ushort4*)(y2 + (size_t)c * PTOT + pb);
            ushort4 u1 = *(const ushort4*)(y2 + (size_t)c * PTOT + pb + 4);
            unsigned short uu[8] = {u0.x, u0.y, u0.z, u0.w, u1.x, u1.y, u1.z, u1.w};
            bf16x8 fr;
            float fs = 0.f;
#pragma unroll
            for (int e = 0; e < 8; ++e) {
                float f = fmaxf(bf2f(uu[e]) * sc[ct] + sh[ct], 0.f);
                fs += f;
                fr[e] = (short)f2bf(f);
            }
            rs[ct] += fs;
            frag[ct] = fr;
        }
#pragma unroll
        for (int i = 0; i < 4; ++i)
#pragma unroll
            for (int j = 0; j < 4; ++j)
                acc[i][j] = __builtin_amdgcn_mfma_f32_16x16x32_bf16(
                    frag[i], frag[j], acc[i][j], 0, 0, 0);
    }
    // s3 partial: combine the 4 k-groups (same lane&15, different lane>>4)
#pragma unroll
    for (int ct = 0; ct < 4; ++ct) {
        rs[ct] += __shfl_xor(rs[ct], 16);
        rs[ct] += __shfl_xor(rs[ct], 32);
    }
    __syncthreads();   // zero-init visible before LDS atomics
#pragma unroll
    for (int i = 0; i < 4; ++i) {
        int c1b = i * 16 + (lane >> 4) * 4;
#pragma unroll
        for (int j = 0; j < 4; ++j) {
            int c2 = j * 16 + (lane & 15);
#pragma unroll
            for (int r = 0; r < 4; ++r)
                atomicAdd(&g3loc[(c1b + r) * 64 + c2], acc[i][j][r]);
        }
    }
    if (lane < 16) {
#pragma unroll
        for (int ct = 0; ct < 4; ++ct) atomicAdd(&s3loc[ct * 16 + lane], rs[ct]);
    }
    __syncthreads();
    for (int i = tid; i < 4096; i += 256) atomicAdd(&G3[i], g3loc[i]);
    if (tid < 64) atomicAdd(&s3[tid], s3loc[tid]);
}

// ---------- finalize3: Gram -> scale3/shift3 ----------
__global__ __launch_bounds__(64) void finalize3_kernel(const float* __restrict__ G3,
                                                       const float* __restrict__ s3,
                                                       const float* __restrict__ w2,
                                                       const float* __restrict__ b2,
                                                       const float* __restrict__ gamma,
                                                       const float* __restrict__ beta,
                                                       float* __restrict__ scale,
                                                       float* __restrict__ shift) {
    int o = blockIdx.x * 64 + threadIdx.x;
    const float* wr = w2 + o * 64;
    double ws = 0.0;
    for (int c = 0; c < 64; ++c) ws += (double)wr[c] * (double)s3[c];
    double qf = 0.0;
    for (int i = 0; i < 64; ++i) {
        double ti = 0.0;
        for (int j = 0; j < 64; ++j) ti += (double)G3[i * 64 + j] * (double)wr[j];
        qf += (double)wr[i] * ti;
    }
    const double invP = 1.0 / (double)PTOT;
    double bb = (double)b2[o];
    double mean = ws * invP + bb;
    double ey2 = qf * invP + 2.0 * bb * (ws * invP) + bb * bb;
    double var = ey2 - mean * mean;
    float sc = gamma[o] / sqrtf((float)var + EPS_);
    scale[o] = sc;
    shift[o] = beta[o] - (float)mean * sc;
}

// ---------- conv3 + bn3 + relu + maxpool, MFMA bf16 (R22, verified) ----------
__global__ __launch_bounds__(256) void conv3_mfma_kernel(const unsigned short* __restrict__ y2,
                                                         const unsigned short* __restrict__ w2bf,
                                                         const float* __restrict__ b2,
                                                         const float* __restrict__ scale2,
                                                         const float* __restrict__ shift2,
                                                         const float* __restrict__ scale3,
                                                         const float* __restrict__ shift3,
                                                         float* __restrict__ out1) {
    __shared__ __align__(16) unsigned short Xt[64 * XT_S];   // [pt][c] bf16
    int tid = threadIdx.x;
    int lane = tid & 63, w = tid >> 6;
    int p0 = blockIdx.x * 64;
    // ---- stage Xt: thread -> point pt=lane, channel block cb = w*16
    {
        int cb = w * 16;
        unsigned short row[16];
#pragma unroll
        for (int j = 0; j < 16; ++j) {
            int c = cb + j;
            float v = bf2f(y2[(size_t)c * PTOT + p0 + lane]);   // coalesced u16
            row[j] = f2bf(fmaxf(v * scale2[c] + shift2[c], 0.f));
        }
#pragma unroll
        for (int qq = 0; qq < 4; ++qq) {
            ushort4 u = make_ushort4(row[4 * qq], row[4 * qq + 1],
                                     row[4 * qq + 2], row[4 * qq + 3]);
            *(ushort4*)&Xt[lane * XT_S + cb + 4 * qq] = u;
        }
    }
    // ---- B-frags (weights) from global (L2-hot, block-invariant)
    int ch0 = (w >> 1) * 64;
    int pt0 = (w & 1) * 32;
    bf16x8 bfrag[4][2];
#pragma unroll
    for (int ct = 0; ct < 4; ++ct)
#pragma unroll
        for (int k = 0; k < 2; ++k)
            bfrag[ct][k] = *(const bf16x8*)(w2bf +
                (size_t)(ch0 + ct * 16 + (lane & 15)) * 64 + k * 32 + (lane >> 4) * 8);
    __syncthreads();
    // ---- A-frags from LDS
    bf16x8 afrag[2][2];
#pragma unroll
    for (int ptt = 0; ptt < 2; ++ptt)
#pragma unroll
        for (int k = 0; k < 2; ++k)
            afrag[ptt][k] = *(const bf16x8*)&Xt[
                (pt0 + ptt * 16 + (lane & 15)) * XT_S + k * 32 + (lane >> 4) * 8];
    // ---- MFMA: 8 C-tiles x K2
    f32x4 acc[2][4];
#pragma unroll
    for (int ptt = 0; ptt < 2; ++ptt)
#pragma unroll
        for (int ct = 0; ct < 4; ++ct) {
            f32x4 a = {0.f, 0.f, 0.f, 0.f};
            a = __builtin_amdgcn_mfma_f32_16x16x32_bf16(afrag[ptt][0], bfrag[ct][0], a, 0, 0, 0);
            a = __builtin_amdgcn_mfma_f32_16x16x32_bf16(afrag[ptt][1], bfrag[ct][1], a, 0, 0, 0);
            acc[ptt][ct] = a;
        }
    // ---- epilogue: affine3 (bias folded) + maxpool over the wave's 32 pts
    int b = p0 >> 15;
    int s = ((p0 & 32767) >> 5) + (w & 1);
#pragma unroll
    for (int ct = 0; ct < 4; ++ct) {
        int o = ch0 + ct * 16 + (lane & 15);
        float sc = scale3[o];
        float sh = __builtin_fmaf(b2[o], sc, shift3[o]);
        float m = __builtin_fmaf(acc[0][ct][0], sc, sh);
#pragma unroll
        for (int r = 1; r < 4; ++r) m = fmaxf(m, __builtin_fmaf(acc[0][ct][r], sc, sh));
#pragma unroll
        for (int r = 0; r < 4; ++r) m = fmaxf(m, __builtin_fmaf(acc[1][ct][r], sc, sh));
        m = fmaxf(m, __shfl_xor(m, 16));
        m = fmaxf(m, __shfl_xor(m, 32));
        if (lane < 16) out1[(size_t)b * 131072 + (size_t)o * 1024 + s] = fmaxf(m, 0.f);
    }
}

extern "C" void kernel_launch(void* const* d_in, const int* in_sizes, int n_in,
                              void* d_out, int out_size, void* d_ws, size_t ws_size,
                              hipStream_t stream) {
    (void)in_sizes; (void)n_in; (void)out_size; (void)ws_size;
    const float* xyz    = (const float*)d_in[0];
    const float* pts    = (const float*)d_in[1];
    const float* w0     = (const float*)d_in[2];
    const float* b0     = (const float*)d_in[3];
    const float* gamma0 = (const float*)d_in[4];
    const float* beta0  = (const float*)d_in[5];
    const float* w1     = (const float*)d_in[6];
    const float* b1     = (const float*)d_in[7];
    const float* gamma1 = (const float*)d_in[8];
    const float* beta1  = (const float*)d_in[9];
    const float* w2     = (const float*)d_in[10];
    const float* b2     = (const float*)d_in[11];
    const float* gamma2 = (const float*)d_in[12];
    const float* beta2  = (const float*)d_in[13];

    char* ws = (char*)d_ws;
    int*   ball_idx = (int*)(ws + 0);                       // 2 MB
    float* partial2 = (float*)(ws + 3145728);               // 4 MB (8192*128)
    float* G3       = (float*)(ws + 7340032);               // 16 KB
    float* s3       = (float*)(ws + 7356416);               // 256 B
    float* g1s1     = (float*)(ws + 7356672);               // 108 B (21+6)
    float* scsh     = (float*)(ws + 7357440);               // 2 KB
    unsigned short* w1bf = (unsigned short*)(ws + 7359488); // 8 KB
    unsigned short* w2bf = (unsigned short*)(ws + 7375872); // 16 KB
    unsigned short* y2 = (unsigned short*)(ws + 7408640);   // 64 MB -> total ~71.5 MB

    float* scale1 = scsh,       *shift1 = scsh + 64;
    float* scale2 = scsh + 128, *shift2 = scsh + 192;
    float* scale3 = scsh + 256, *shift3 = scsh + 384;

    float* out0 = (float*)d_out;                 // (B,3,NPOINT)
    float* out1 = out0 + B_ * 3 * NPOINT_;       // (B,128,NPOINT)

    hipLaunchKernelGGL(prep_kernel, dim3(32), dim3(256), 0, stream, w1, w2, w1bf, w2bf, G3);
    hipLaunchKernelGGL(fps_kernel, dim3(B_), dim3(1024), 0, stream, xyz, out0);
    hipLaunchKernelGGL(ball_kernel, dim3(2048), dim3(256), 0, stream, xyz, out0, ball_idx);
    hipLaunchKernelGGL(gram1_kernel, dim3(512), dim3(256), 0, stream,
                       xyz, pts, out0, ball_idx, g1s1);
    hipLaunchKernelGGL(finalize1_kernel, dim3(1), dim3(64), 0, stream,
                       g1s1, w0, b0, gamma0, beta0, scale1, shift1);
    hipLaunchKernelGGL(conv2_mfma_kernel, dim3(8192), dim3(256), 0, stream,
                       xyz, pts, out0, ball_idx, w0, b0, w1bf, b1, scale1, shift1, y2, partial2);
    hipLaunchKernelGGL(reduce_finalize_kernel, dim3(64), dim3(256), 0, stream,
                       partial2, 8192, gamma1, beta1, scale2, shift2);
    hipLaunchKernelGGL(gram3_mfma_kernel, dim3(512), dim3(256), 0, stream,
                       y2, scale2, shift2, G3, s3);
    hipLaunchKernelGGL(finalize3_kernel, dim3(2), dim3(64), 0, stream,
                       G3, s3, w2, b2, gamma2, beta2, scale3, shift3);
    hipLaunchKernelGGL(conv3_mfma_kernel, dim3(8192), dim3(256), 0, stream,
                       y2, w2bf, b2, scale2, shift2, scale3, shift3, out1);
}

// Round 14
// 1012.225 us; speedup vs baseline: 1.2429x; 1.2429x over previous
//
#include <hip/hip_runtime.h>
#include <stdint.h>

#define B_ 16
#define N_ 4096
#define NPOINT_ 1024
#define NSAMPLE_ 32
#define PPB 32768            // NPOINT_*NSAMPLE_
#define PTOT 524288          // B_*PPB
#define EPS_ 1e-5f

typedef float v2f __attribute__((ext_vector_type(2)));
typedef __attribute__((ext_vector_type(8))) short bf16x8;
typedef __attribute__((ext_vector_type(4))) float f32x4;

// ---------- bf16 helpers ----------
__device__ __forceinline__ float bf2f(unsigned short h) {
    unsigned int u = ((unsigned int)h) << 16;
    float f; __builtin_memcpy(&f, &u, 4); return f;
}
__device__ __forceinline__ unsigned short f2bf(float f) {
    unsigned int u; __builtin_memcpy(&u, &f, 4);
    u = (u + 0x7fffu + ((u >> 16) & 1u)) >> 16;   // RNE
    return (unsigned short)u;
}

// ---------- prep: zero G3/s3/G1/s1, cast w1,w2 -> bf16 ----------
__global__ __launch_bounds__(256) void prep_kernel(const float* __restrict__ w1,
                                                   const float* __restrict__ w2,
                                                   unsigned short* __restrict__ w1bf,
                                                   unsigned short* __restrict__ w2bf,
                                                   float* __restrict__ g3s3) {
    int i = blockIdx.x * 256 + threadIdx.x;   // 32 blocks -> 8192
    if (i < 4187) g3s3[i] = 0.f;
    if (i < 4096) w1bf[i] = f2bf(w1[i]);
    if (i < 8192) w2bf[i] = f2bf(w2[i]);
}

// ---------- FPS (R19/R24/R26 form — 512 thr / 8 waves, measured optimum) ----------
// Wave-count sweep complete: 4w=670, 8w=587, 16w=838 us. Barrier cost scales
// with participants; 8 waves balances issue vs latency hiding. All structural
// alternatives falsified: 2-batch/block (R18 +84%), coord-carry (R15 +13%),
// spin-poll (R25 +24%), 16 waves (R27 +43%).
#define DPP_U32_MAX(ctrl)                                                          \
    {                                                                              \
        unsigned int n = (unsigned int)__builtin_amdgcn_update_dpp(                \
            (int)mb, (int)mb, ctrl, 0xF, 0xF, false);                              \
        mb = (n > mb) ? n : mb;                                                    \
    }

// max tree over 8 per-wave keys; ties across waves resolved by ~idx low word
#define TREE8(RED, CUR)                                                            \
    {                                                                              \
        const ulonglong2* rp = (const ulonglong2*)&RED[t & 1][0];                  \
        ulonglong2 r0 = rp[0], r1 = rp[1], r2 = rp[2], r3 = rp[3];                 \
        unsigned long long a0 = (r0.x > r0.y) ? r0.x : r0.y;                       \
        unsigned long long a1 = (r1.x > r1.y) ? r1.x : r1.y;                       \
        unsigned long long a2 = (r2.x > r2.y) ? r2.x : r2.y;                       \
        unsigned long long a3 = (r3.x > r3.y) ? r3.x : r3.y;                       \
        unsigned long long b0 = (a0 > a1) ? a0 : a1;                               \
        unsigned long long b1 = (a2 > a3) ? a2 : a3;                               \
        unsigned long long mm = (b0 > b1) ? b0 : b1;                               \
        CUR = (int)(~(unsigned int)mm) & (N_ - 1);                                 \
    }

__global__ __launch_bounds__(512) void fps_kernel(const float* __restrict__ xyz,
                                                  float* __restrict__ out0) {
    const int b = blockIdx.x;
    const int tid = threadIdx.x;
    const int lane = tid & 63, wid = tid >> 6;   // wid 0..7
    __shared__ float sx[N_], sy[N_], sz[N_];
    __shared__ __align__(16) unsigned long long red[2][8];
    __shared__ int sidx[NPOINT_];
    const float* xb = xyz + (size_t)b * 3 * N_;
    for (int p = tid; p < N_; p += 512) {
        sx[p] = xb[p]; sy[p] = xb[N_ + p]; sz[p] = xb[2 * N_ + p];
    }
    __syncthreads();
    // slot s = j*2+k covers point index tid + s*512 (ascending in s)
    v2f px2[4], py2[4], pz2[4], md2[4];
#pragma unroll
    for (int j = 0; j < 4; ++j) {
        int p = tid + j * 1024;
        px2[j][0] = sx[p];       px2[j][1] = sx[p + 512];
        py2[j][0] = sy[p];       py2[j][1] = sy[p + 512];
        pz2[j][0] = sz[p];       pz2[j][1] = sz[p + 512];
        md2[j][0] = 1e10f;       md2[j][1] = 1e10f;
    }
    int cur = 0;
    for (int t = 0; t < NPOINT_; ++t) {
        if (tid == 0) sidx[t] = cur;           // LDS only — no vmcnt on the loop
        float cx = sx[cur], cy = sy[cur], cz = sz[cur];
        v2f c2x; c2x[0] = cx; c2x[1] = cx;
        v2f c2y; c2y[0] = cy; c2y[1] = cy;
        v2f c2z; c2z[0] = cz; c2z[1] = cz;
#pragma unroll
        for (int j = 0; j < 4; ++j) {
            // pk sub/mul/fma/min: per-element rounding identical to the
            // scalar __fmul_rn/__builtin_fmaf chain -> same selection
            v2f dx = px2[j] - c2x;
            v2f dy = py2[j] - c2y;
            v2f dz = pz2[j] - c2z;
            v2f t0 = dx * dx;
            v2f t1 = __builtin_elementwise_fma(dy, dy, t0);
            v2f d2 = __builtin_elementwise_fma(dz, dz, t1);
            md2[j] = __builtin_elementwise_min(md2[j], d2);
        }
        // lane-local max of the 8 running minima (value only)
        v2f m01 = __builtin_elementwise_max(md2[0], md2[1]);
        v2f m23 = __builtin_elementwise_max(md2[2], md2[3]);
        v2f mq  = __builtin_elementwise_max(m01, m23);
        float lm = fmaxf(mq[0], mq[1]);
        unsigned int mb; __builtin_memcpy(&mb, &lm, 4);   // >=0 -> monotone bits
        DPP_U32_MAX(0x111)   // row_shr:1
        DPP_U32_MAX(0x112)   // row_shr:2
        DPP_U32_MAX(0x114)   // row_shr:4
        DPP_U32_MAX(0x118)   // row_shr:8
        DPP_U32_MAX(0x142)   // row_bcast:15
        DPP_U32_MAX(0x143)   // row_bcast:31
        unsigned int Mw = (unsigned int)__builtin_amdgcn_readlane((int)mb, 63);
        // equality ballots in slot order; results are wave-uniform (SGPR)
        unsigned long long bm[8];
#pragma unroll
        for (int j = 0; j < 4; ++j) {
#pragma unroll
            for (int k = 0; k < 2; ++k) {
                float f = md2[j][k];
                unsigned int v; __builtin_memcpy(&v, &f, 4);
                bm[j * 2 + k] = __ballot(v == Mw);
            }
        }
        // first nonzero slot (ascending) + lowest lane = smallest index among
        // ties; pure SALU select chain (uniform values)
        int off = 0; unsigned long long sel = 0;
#pragma unroll
        for (int s = 7; s >= 0; --s)
            if (bm[s] != 0ull) { sel = bm[s]; off = s; }
        int bi = off * 512 + wid * 64 + (int)__builtin_ctzll(sel);
        unsigned long long key =
            ((unsigned long long)Mw << 32) | (unsigned int)~bi;
        if (lane == 0) red[t & 1][wid] = key;   // key is wave-uniform
        __syncthreads();
        TREE8(red, cur)
    }
    __syncthreads();
    // coalesced epilogue: gather centers from LDS, store once
    for (int t = tid; t < NPOINT_; t += 512) {
        int ix = sidx[t];
        out0[(size_t)b * 3 * NPOINT_ + t]               = sx[ix];
        out0[(size_t)b * 3 * NPOINT_ + NPOINT_ + t]     = sy[ix];
        out0[(size_t)b * 3 * NPOINT_ + 2 * NPOINT_ + t] = sz[ix];
    }
}

// ---------- ball query (R26: 2 queries per wave — share the point stream) ----------
__global__ __launch_bounds__(256) void ball_kernel(const float* __restrict__ xyz,
                                                   const float* __restrict__ out0,
                                                   int* __restrict__ ball_idx) {
    int gid  = (blockIdx.x * 256 + threadIdx.x) >> 6;   // 2048 blocks -> 8192 gids
    int lane = threadIdx.x & 63;
    int b = gid >> 9, s0 = (gid & 511) * 2;
    const float* xb = xyz + (size_t)b * 3 * N_;
    float q0x = out0[(size_t)b * 3 * NPOINT_ + s0];
    float q0y = out0[(size_t)b * 3 * NPOINT_ + NPOINT_ + s0];
    float q0z = out0[(size_t)b * 3 * NPOINT_ + 2 * NPOINT_ + s0];
    float q1x = out0[(size_t)b * 3 * NPOINT_ + s0 + 1];
    float q1y = out0[(size_t)b * 3 * NPOINT_ + NPOINT_ + s0 + 1];
    float q1z = out0[(size_t)b * 3 * NPOINT_ + 2 * NPOINT_ + s0 + 1];
    float qs0 = __builtin_fmaf(q0z, q0z, __builtin_fmaf(q0y, q0y, __fmul_rn(q0x, q0x)));
    float qs1 = __builtin_fmaf(q1z, q1z, __builtin_fmaf(q1y, q1y, __fmul_rn(q1x, q1x)));
    int cnt0 = 0, first0 = 0, cnt1 = 0, first1 = 0;
    int* outp0 = ball_idx + ((size_t)b * NPOINT_ + s0) * NSAMPLE_;
    int* outp1 = outp0 + NSAMPLE_;
#pragma unroll 2
    for (int n0 = 0; n0 < N_; n0 += 64) {
        int n = n0 + lane;
        float px = xb[n], py = xb[N_ + n], pz = xb[2 * N_ + n];
        float ps  = __builtin_fmaf(pz, pz, __builtin_fmaf(py, py, __fmul_rn(px, px)));
        float dot0 = __builtin_fmaf(q0z, pz, __builtin_fmaf(q0y, py, __fmul_rn(q0x, px)));
        float d0   = __fadd_rn(__builtin_fmaf(-2.f, dot0, qs0), ps);
        float dot1 = __builtin_fmaf(q1z, pz, __builtin_fmaf(q1y, py, __fmul_rn(q1x, px)));
        float d1   = __fadd_rn(__builtin_fmaf(-2.f, dot1, qs1), ps);
        bool ok0 = !(d0 > 0.04f);
        bool ok1 = !(d1 > 0.04f);
        unsigned long long m0 = __ballot(ok0);
        unsigned long long m1 = __ballot(ok1);
        if (m0) {
            if (cnt0 == 0) first0 = n0 + (__ffsll((unsigned long long)m0) - 1);
            if (ok0) {
                int r = __popcll(m0 & ((1ull << lane) - 1ull));
                int pos = cnt0 + r;
                if (pos < NSAMPLE_) outp0[pos] = n;
            }
            cnt0 += __popcll(m0);
        }
        if (m1) {
            if (cnt1 == 0) first1 = n0 + (__ffsll((unsigned long long)m1) - 1);
            if (ok1) {
                int r = __popcll(m1 & ((1ull << lane) - 1ull));
                int pos = cnt1 + r;
                if (pos < NSAMPLE_) outp1[pos] = n;
            }
            cnt1 += __popcll(m1);
        }
    }
    if (cnt0 < NSAMPLE_) {
        for (int pos = cnt0 + lane; pos < NSAMPLE_; pos += 64) outp0[pos] = first0;
    }
    if (cnt1 < NSAMPLE_) {
        for (int pos = cnt1 + lane; pos < NSAMPLE_; pos += 64) outp1[pos] = first1;
    }
}

// ---------- gram1: G1 = sum x x^T (6x6 upper tri, 21) + s1 = sum x (6) ----------
__global__ __launch_bounds__(256) void gram1_kernel(const float* __restrict__ xyz,
                                                    const float* __restrict__ pts,
                                                    const float* __restrict__ out0,
                                                    const int* __restrict__ ball_idx,
                                                    float* __restrict__ g1s1) {
    __shared__ float red[4][27];
    int tid = threadIdx.x;
    int lane = tid & 63, w = tid >> 6;
    float a[27];
#pragma unroll
    for (int i = 0; i < 27; ++i) a[i] = 0.f;
    for (int k = 0; k < 4; ++k) {
        int p = blockIdx.x * 1024 + k * 256 + tid;
        int b = p >> 15, s = (p & 32767) >> 5;
        int gi = ball_idx[p];
        const float* xb = xyz + (size_t)b * 3 * N_;
        const float* pb = pts + (size_t)b * 3 * N_;
        float x[6];
        x[0] = xb[gi]          - out0[(size_t)b * 3 * NPOINT_ + s];
        x[1] = xb[N_ + gi]     - out0[(size_t)b * 3 * NPOINT_ + NPOINT_ + s];
        x[2] = xb[2 * N_ + gi] - out0[(size_t)b * 3 * NPOINT_ + 2 * NPOINT_ + s];
        x[3] = pb[gi]; x[4] = pb[N_ + gi]; x[5] = pb[2 * N_ + gi];
        int idx = 0;
#pragma unroll
        for (int i = 0; i < 6; ++i)
#pragma unroll
            for (int j = i; j < 6; ++j) {
                a[idx] = __builtin_fmaf(x[i], x[j], a[idx]);
                ++idx;
            }
#pragma unroll
        for (int i = 0; i < 6; ++i) a[21 + i] += x[i];
    }
#pragma unroll
    for (int i = 0; i < 27; ++i) {
#pragma unroll
        for (int off = 32; off >= 1; off >>= 1)
            a[i] += __shfl_down(a[i], off);
    }
    if (lane == 0) {
#pragma unroll
        for (int i = 0; i < 27; ++i) red[w][i] = a[i];
    }
    __syncthreads();
    if (tid < 27)
        atomicAdd(&g1s1[tid], red[0][tid] + red[1][tid] + red[2][tid] + red[3][tid]);
}

// ---------- finalize1: G1/s1 -> scale1/shift1 (double, finalize3 pattern) ----------
__global__ __launch_bounds__(64) void finalize1_kernel(const float* __restrict__ g1s1,
                                                       const float* __restrict__ w0,
                                                       const float* __restrict__ b0,
                                                       const float* __restrict__ gamma,
                                                       const float* __restrict__ beta,
                                                       float* __restrict__ scale,
                                                       float* __restrict__ shift) {
    int o = threadIdx.x;
    const float* wr = w0 + o * 6;
    double G[6][6];
    {
        int idx = 0;
        for (int i = 0; i < 6; ++i)
            for (int j = i; j < 6; ++j) { G[i][j] = G[j][i] = (double)g1s1[idx]; ++idx; }
    }
    double ws = 0.0;
    for (int c = 0; c < 6; ++c) ws += (double)wr[c] * (double)g1s1[21 + c];
    double qf = 0.0;
    for (int i = 0; i < 6; ++i) {
        double ti = 0.0;
        for (int j = 0; j < 6; ++j) ti += G[i][j] * (double)wr[j];
        qf += (double)wr[i] * ti;
    }
    const double invP = 1.0 / (double)PTOT;
    double bb = (double)b0[o];
    double mean = ws * invP + bb;
    double ey2 = qf * invP + 2.0 * bb * (ws * invP) + bb * bb;
    double var = ey2 - mean * mean;
    float sc = gamma[o] / sqrtf((float)var + EPS_);
    scale[o] = sc;
    shift[o] = beta[o] - (float)mean * sc;
}

// ---------- reduce partials -> scale/shift (used for layer 2) ----------
__global__ __launch_bounds__(256) void reduce_finalize_kernel(const float* __restrict__ partials,
                                                              int nblocks,
                                                              const float* __restrict__ gamma,
                                                              const float* __restrict__ beta,
                                                              float* __restrict__ scale,
                                                              float* __restrict__ shift) {
    int c = blockIdx.x;
    int tid = threadIdx.x, lane = tid & 63, wid = tid >> 6;
    float s1 = 0.f, s2 = 0.f;
    for (int i = tid; i < nblocks; i += 256) {
        s1 += partials[(size_t)i * 128 + c];
        s2 += partials[(size_t)i * 128 + 64 + c];
    }
#pragma unroll
    for (int off = 32; off >= 1; off >>= 1) {
        s1 += __shfl_down(s1, off);
        s2 += __shfl_down(s2, off);
    }
    __shared__ float r1[4], r2[4];
    if (lane == 0) { r1[wid] = s1; r2[wid] = s2; }
    __syncthreads();
    if (tid == 0) {
        float S1 = r1[0] + r1[1] + r1[2] + r1[3];
        float S2 = r2[0] + r2[1] + r2[2] + r2[3];
        const float inv = 1.f / (float)PTOT;
        float m = S1 * inv;
        float v = S2 * inv - m * m;
        float sc = gamma[c] / sqrtf(v + EPS_);
        scale[c] = sc;
        shift[c] = beta[c] - m * sc;
    }
}

// ---------- conv2 (R24 MFMA; R25 staging spread — kept) ----------
#define XT_S 72
__global__ __launch_bounds__(256) void conv2_mfma_kernel(const float* __restrict__ xyz,
                                                         const float* __restrict__ pts,
                                                         const float* __restrict__ out0,
                                                         const int* __restrict__ ball_idx,
                                                         const float* __restrict__ w0,
                                                         const float* __restrict__ b0,
                                                         const unsigned short* __restrict__ w1bf,
                                                         const float* __restrict__ b1,
                                                         const float* __restrict__ scale1,
                                                         const float* __restrict__ shift1,
                                                         unsigned short* __restrict__ y2,
                                                         float* __restrict__ partial2) {
    __shared__ float sw0[448];
    __shared__ float x1s[6 * 64];
    __shared__ __align__(16) unsigned short Xt[64 * XT_S];   // [p][c] bf16
    __shared__ float ssc[64], ssh[64], sb1[64];
    __shared__ float lsum[2][64], lsq[2][64];
    int tid = threadIdx.x;
    int lane = tid & 63, w = tid >> 6;
    int p0 = blockIdx.x * 64;
    for (int i = tid; i < 448; i += 256) sw0[i] = (i < 384) ? w0[i] : b0[i - 384];
    if (tid < 64) { ssc[tid] = scale1[tid]; ssh[tid] = shift1[tid]; sb1[tid] = b1[tid]; }
    // 384 gather items spread over 256 threads
    for (int it = tid; it < 384; it += 256) {
        int ch = it >> 6, p = it & 63;
        int pp = p0 + p;
        int b = pp >> 15, s = (pp & 32767) >> 5;
        int gi = ball_idx[pp];
        float v;
        if (ch < 3)
            v = xyz[(size_t)b * 3 * N_ + (size_t)ch * N_ + gi]
              - out0[(size_t)b * 3 * NPOINT_ + (size_t)ch * NPOINT_ + s];
        else
            v = pts[(size_t)b * 3 * N_ + (size_t)(ch - 3) * N_ + gi];
        x1s[ch * 64 + p] = v;
    }
    // A-frags (weights) from global while x1s staging settles
    int o0 = (w >> 1) * 32, pq0 = (w & 1) * 32;
    bf16x8 afrag[2][2];
#pragma unroll
    for (int ot = 0; ot < 2; ++ot)
#pragma unroll
        for (int k = 0; k < 2; ++k)
            afrag[ot][k] = *(const bf16x8*)(w1bf +
                (size_t)(o0 + ot * 16 + (lane & 15)) * 64 + k * 32 + (lane >> 4) * 8);
    __syncthreads();
    // stage 1: thread -> point p=lane, channels cb..cb+15 (K=6 VALU GEMM)
    {
        int p = lane, cb = w * 16;
        float v0 = x1s[p], v1 = x1s[64 + p], v2 = x1s[128 + p];
        float v3 = x1s[192 + p], v4 = x1s[256 + p], v5 = x1s[320 + p];
        unsigned short row[16];
#pragma unroll
        for (int j = 0; j < 16; ++j) {
            int c = cb + j;
            float a = sw0[384 + c];
            a += sw0[c * 6 + 0] * v0; a += sw0[c * 6 + 1] * v1; a += sw0[c * 6 + 2] * v2;
            a += sw0[c * 6 + 3] * v3; a += sw0[c * 6 + 4] * v4; a += sw0[c * 6 + 5] * v5;
            row[j] = f2bf(fmaxf(a * ssc[c] + ssh[c], 0.f));
        }
#pragma unroll
        for (int qq = 0; qq < 4; ++qq) {
            ushort4 u = make_ushort4(row[4 * qq], row[4 * qq + 1],
                                     row[4 * qq + 2], row[4 * qq + 3]);
            *(ushort4*)&Xt[p * XT_S + cb + 4 * qq] = u;
        }
    }
    __syncthreads();
    // B-frags from LDS
    bf16x8 bfrag[2][2];
#pragma unroll
    for (int pt = 0; pt < 2; ++pt)
#pragma unroll
        for (int k = 0; k < 2; ++k)
            bfrag[pt][k] = *(const bf16x8*)&Xt[
                (pq0 + pt * 16 + (lane & 15)) * XT_S + k * 32 + (lane >> 4) * 8];
    // MFMA: D[o][p]
    f32x4 acc[2][2];
#pragma unroll
    for (int ot = 0; ot < 2; ++ot)
#pragma unroll
        for (int pt = 0; pt < 2; ++pt) {
            f32x4 a = {0.f, 0.f, 0.f, 0.f};
            a = __builtin_amdgcn_mfma_f32_16x16x32_bf16(afrag[ot][0], bfrag[pt][0], a, 0, 0, 0);
            a = __builtin_amdgcn_mfma_f32_16x16x32_bf16(afrag[ot][1], bfrag[pt][1], a, 0, 0, 0);
            acc[ot][pt] = a;
        }
    // epilogue: +b1, y2 store (bf16), stats over p
#pragma unroll
    for (int ot = 0; ot < 2; ++ot) {
        float sA[4] = {0.f, 0.f, 0.f, 0.f}, sQ[4] = {0.f, 0.f, 0.f, 0.f};
#pragma unroll
        for (int pt = 0; pt < 2; ++pt) {
            int p = pq0 + pt * 16 + (lane & 15);
#pragma unroll
            for (int r = 0; r < 4; ++r) {
                int o = o0 + ot * 16 + (lane >> 4) * 4 + r;
                float val = acc[ot][pt][r] + sb1[o];
                y2[(size_t)o * PTOT + p0 + p] = f2bf(val);
                sA[r] += val;
                sQ[r] = __builtin_fmaf(val, val, sQ[r]);
            }
        }
#pragma unroll
        for (int off2 = 8; off2 >= 1; off2 >>= 1)
#pragma unroll
            for (int r = 0; r < 4; ++r) {
                sA[r] += __shfl_down(sA[r], off2);
                sQ[r] += __shfl_down(sQ[r], off2);
            }
        if ((lane & 15) == 0) {
#pragma unroll
            for (int r = 0; r < 4; ++r) {
                int o = o0 + ot * 16 + (lane >> 4) * 4 + r;
                lsum[w & 1][o] = sA[r];
                lsq[w & 1][o] = sQ[r];
            }
        }
    }
    __syncthreads();
    if (tid < 64)
        partial2[(size_t)blockIdx.x * 128 + tid] = lsum[0][tid] + lsum[1][tid];
    else if (tid < 128)
        partial2[(size_t)blockIdx.x * 128 + tid] = lsq[0][tid - 64] + lsq[1][tid - 64];
}

// ---------- gram3 (R23: MFMA, no LDS staging — verified) ----------
__global__ __launch_bounds__(256) void gram3_mfma_kernel(const unsigned short* __restrict__ y2,
                                                         const float* __restrict__ scale2,
                                                         const float* __restrict__ shift2,
                                                         float* __restrict__ G3,
                                                         float* __restrict__ s3) {
    __shared__ float g3loc[4096];
    __shared__ float s3loc[64];
    int tid = threadIdx.x;
    int lane = tid & 63, w = tid >> 6;
    for (int i = tid; i < 4096; i += 256) g3loc[i] = 0.f;
    if (tid < 64) s3loc[tid] = 0.f;
    float sc[4], sh[4];
#pragma unroll
    for (int ct = 0; ct < 4; ++ct) {
        int c = ct * 16 + (lane & 15);
        sc[ct] = scale2[c]; sh[ct] = shift2[c];
    }
    f32x4 acc[4][4];
#pragma unroll
    for (int i = 0; i < 4; ++i)
#pragma unroll
        for (int j = 0; j < 4; ++j) acc[i][j] = (f32x4){0.f, 0.f, 0.f, 0.f};
    float rs[4] = {0.f, 0.f, 0.f, 0.f};
    int pw0 = blockIdx.x * 1024 + w * 256;   // wave: 256 points = 8 chunks of 32
    for (int chk = 0; chk < 8; ++chk) {
        int pb = pw0 + chk * 32 + (lane >> 4) * 8;
        bf16x8 frag[4];
#pragma unroll
        for (int ct = 0; ct < 4; ++ct) {
            int c = ct * 16 + (lane & 15);
            ushort4 u0 = *(const ushort4*)(y2 + (size_t)c * PTOT + pb);
            ushort4 u1 = *(const ushort4*)(y2 + (size_t)c * PTOT + pb + 4);
            unsigned short uu[8] = {u0.x, u0.y, u0.z, u0.w, u1.x, u1.y, u1.z, u1.w};
            bf16x8 fr;
            float fs = 0.f;
#pragma unroll
            for (int e = 0; e < 8; ++e) {
                float f = fmaxf(bf2f(uu[e]) * sc[ct] + sh[ct], 0.f);
                fs += f;
                fr[e] = (short)f2bf(f);
            }
            rs[ct] += fs;
            frag[ct] = fr;
        }
#pragma unroll
        for (int i = 0; i < 4; ++i)
#pragma unroll
            for (int j = 0; j < 4; ++j)
                acc[i][j] = __builtin_amdgcn_mfma_f32_16x16x32_bf16(
                    frag[i], frag[j], acc[i][j], 0, 0, 0);
    }
    // s3 partial: combine the 4 k-groups (same lane&15, different lane>>4)
#pragma unroll
    for (int ct = 0; ct < 4; ++ct) {
        rs[ct] += __shfl_xor(rs[ct], 16);
        rs[ct] += __shfl_xor(rs[ct], 32);
    }
    __syncthreads();   // zero-init visible before LDS atomics
#pragma unroll
    for (int i = 0; i < 4; ++i) {
        int c1b = i * 16 + (lane >> 4) * 4;
#pragma unroll
        for (int j = 0; j < 4; ++j) {
            int c2 = j * 16 + (lane & 15);
#pragma unroll
            for (int r = 0; r < 4; ++r)
                atomicAdd(&g3loc[(c1b + r) * 64 + c2], acc[i][j][r]);
        }
    }
    if (lane < 16) {
#pragma unroll
        for (int ct = 0; ct < 4; ++ct) atomicAdd(&s3loc[ct * 16 + lane], rs[ct]);
    }
    __syncthreads();
    for (int i = tid; i < 4096; i += 256) atomicAdd(&G3[i], g3loc[i]);
    if (tid < 64) atomicAdd(&s3[tid], s3loc[tid]);
}

// ---------- finalize3: Gram -> scale3/shift3 ----------
__global__ __launch_bounds__(64) void finalize3_kernel(const float* __restrict__ G3,
                                                       const float* __restrict__ s3,
                                                       const float* __restrict__ w2,
                                                       const float* __restrict__ b2,
                                                       const float* __restrict__ gamma,
                                                       const float* __restrict__ beta,
                                                       float* __restrict__ scale,
                                                       float* __restrict__ shift) {
    int o = blockIdx.x * 64 + threadIdx.x;
    const float* wr = w2 + o * 64;
    double ws = 0.0;
    for (int c = 0; c < 64; ++c) ws += (double)wr[c] * (double)s3[c];
    double qf = 0.0;
    for (int i = 0; i < 64; ++i) {
        double ti = 0.0;
        for (int j = 0; j < 64; ++j) ti += (double)G3[i * 64 + j] * (double)wr[j];
        qf += (double)wr[i] * ti;
    }
    const double invP = 1.0 / (double)PTOT;
    double bb = (double)b2[o];
    double mean = ws * invP + bb;
    double ey2 = qf * invP + 2.0 * bb * (ws * invP) + bb * bb;
    double var = ey2 - mean * mean;
    float sc = gamma[o] / sqrtf((float)var + EPS_);
    scale[o] = sc;
    shift[o] = beta[o] - (float)mean * sc;
}

// ---------- conv3 + bn3 + relu + maxpool, MFMA bf16 (R22, verified) ----------
__global__ __launch_bounds__(256) void conv3_mfma_kernel(const unsigned short* __restrict__ y2,
                                                         const unsigned short* __restrict__ w2bf,
                                                         const float* __restrict__ b2,
                                                         const float* __restrict__ scale2,
                                                         const float* __restrict__ shift2,
                                                         const float* __restrict__ scale3,
                                                         const float* __restrict__ shift3,
                                                         float* __restrict__ out1) {
    __shared__ __align__(16) unsigned short Xt[64 * XT_S];   // [pt][c] bf16
    int tid = threadIdx.x;
    int lane = tid & 63, w = tid >> 6;
    int p0 = blockIdx.x * 64;
    // ---- stage Xt: thread -> point pt=lane, channel block cb = w*16
    {
        int cb = w * 16;
        unsigned short row[16];
#pragma unroll
        for (int j = 0; j < 16; ++j) {
            int c = cb + j;
            float v = bf2f(y2[(size_t)c * PTOT + p0 + lane]);   // coalesced u16
            row[j] = f2bf(fmaxf(v * scale2[c] + shift2[c], 0.f));
        }
#pragma unroll
        for (int qq = 0; qq < 4; ++qq) {
            ushort4 u = make_ushort4(row[4 * qq], row[4 * qq + 1],
                                     row[4 * qq + 2], row[4 * qq + 3]);
            *(ushort4*)&Xt[lane * XT_S + cb + 4 * qq] = u;
        }
    }
    // ---- B-frags (weights) from global (L2-hot, block-invariant)
    int ch0 = (w >> 1) * 64;
    int pt0 = (w & 1) * 32;
    bf16x8 bfrag[4][2];
#pragma unroll
    for (int ct = 0; ct < 4; ++ct)
#pragma unroll
        for (int k = 0; k < 2; ++k)
            bfrag[ct][k] = *(const bf16x8*)(w2bf +
                (size_t)(ch0 + ct * 16 + (lane & 15)) * 64 + k * 32 + (lane >> 4) * 8);
    __syncthreads();
    // ---- A-frags from LDS
    bf16x8 afrag[2][2];
#pragma unroll
    for (int ptt = 0; ptt < 2; ++ptt)
#pragma unroll
        for (int k = 0; k < 2; ++k)
            afrag[ptt][k] = *(const bf16x8*)&Xt[
                (pt0 + ptt * 16 + (lane & 15)) * XT_S + k * 32 + (lane >> 4) * 8];
    // ---- MFMA: 8 C-tiles x K2
    f32x4 acc[2][4];
#pragma unroll
    for (int ptt = 0; ptt < 2; ++ptt)
#pragma unroll
        for (int ct = 0; ct < 4; ++ct) {
            f32x4 a = {0.f, 0.f, 0.f, 0.f};
            a = __builtin_amdgcn_mfma_f32_16x16x32_bf16(afrag[ptt][0], bfrag[ct][0], a, 0, 0, 0);
            a = __builtin_amdgcn_mfma_f32_16x16x32_bf16(afrag[ptt][1], bfrag[ct][1], a, 0, 0, 0);
            acc[ptt][ct] = a;
        }
    // ---- epilogue: affine3 (bias folded) + maxpool over the wave's 32 pts
    int b = p0 >> 15;
    int s = ((p0 & 32767) >> 5) + (w & 1);
#pragma unroll
    for (int ct = 0; ct < 4; ++ct) {
        int o = ch0 + ct * 16 + (lane & 15);
        float sc = scale3[o];
        float sh = __builtin_fmaf(b2[o], sc, shift3[o]);
        float m = __builtin_fmaf(acc[0][ct][0], sc, sh);
#pragma unroll
        for (int r = 1; r < 4; ++r) m = fmaxf(m, __builtin_fmaf(acc[0][ct][r], sc, sh));
#pragma unroll
        for (int r = 0; r < 4; ++r) m = fmaxf(m, __builtin_fmaf(acc[1][ct][r], sc, sh));
        m = fmaxf(m, __shfl_xor(m, 16));
        m = fmaxf(m, __shfl_xor(m, 32));
        if (lane < 16) out1[(size_t)b * 131072 + (size_t)o * 1024 + s] = fmaxf(m, 0.f);
    }
}

extern "C" void kernel_launch(void* const* d_in, const int* in_sizes, int n_in,
                              void* d_out, int out_size, void* d_ws, size_t ws_size,
                              hipStream_t stream) {
    (void)in_sizes; (void)n_in; (void)out_size; (void)ws_size;
    const float* xyz    = (const float*)d_in[0];
    const float* pts    = (const float*)d_in[1];
    const float* w0     = (const float*)d_in[2];
    const float* b0     = (const float*)d_in[3];
    const float* gamma0 = (const float*)d_in[4];
    const float* beta0  = (const float*)d_in[5];
    const float* w1     = (const float*)d_in[6];
    const float* b1     = (const float*)d_in[7];
    const float* gamma1 = (const float*)d_in[8];
    const float* beta1  = (const float*)d_in[9];
    const float* w2     = (const float*)d_in[10];
    const float* b2     = (const float*)d_in[11];
    const float* gamma2 = (const float*)d_in[12];
    const float* beta2  = (const float*)d_in[13];

    char* ws = (char*)d_ws;
    int*   ball_idx = (int*)(ws + 0);                       // 2 MB
    float* partial2 = (float*)(ws + 3145728);               // 4 MB (8192*128)
    float* G3       = (float*)(ws + 7340032);               // 16 KB
    float* s3       = (float*)(ws + 7356416);               // 256 B
    float* g1s1     = (float*)(ws + 7356672);               // 108 B (21+6)
    float* scsh     = (float*)(ws + 7357440);               // 2 KB
    unsigned short* w1bf = (unsigned short*)(ws + 7359488); // 8 KB
    unsigned short* w2bf = (unsigned short*)(ws + 7375872); // 16 KB
    unsigned short* y2 = (unsigned short*)(ws + 7408640);   // 64 MB -> total ~71.5 MB

    float* scale1 = scsh,       *shift1 = scsh + 64;
    float* scale2 = scsh + 128, *shift2 = scsh + 192;
    float* scale3 = scsh + 256, *shift3 = scsh + 384;

    float* out0 = (float*)d_out;                 // (B,3,NPOINT)
    float* out1 = out0 + B_ * 3 * NPOINT_;       // (B,128,NPOINT)

    hipLaunchKernelGGL(prep_kernel, dim3(32), dim3(256), 0, stream, w1, w2, w1bf, w2bf, G3);
    hipLaunchKernelGGL(fps_kernel, dim3(B_), dim3(512), 0, stream, xyz, out0);
    hipLaunchKernelGGL(ball_kernel, dim3(2048), dim3(256), 0, stream, xyz, out0, ball_idx);
    hipLaunchKernelGGL(gram1_kernel, dim3(512), dim3(256), 0, stream,
                       xyz, pts, out0, ball_idx, g1s1);
    hipLaunchKernelGGL(finalize1_kernel, dim3(1), dim3(64), 0, stream,
                       g1s1, w0, b0, gamma0, beta0, scale1, shift1);
    hipLaunchKernelGGL(conv2_mfma_kernel, dim3(8192), dim3(256), 0, stream,
                       xyz, pts, out0, ball_idx, w0, b0, w1bf, b1, scale1, shift1, y2, partial2);
    hipLaunchKernelGGL(reduce_finalize_kernel, dim3(64), dim3(256), 0, stream,
                       partial2, 8192, gamma1, beta1, scale2, shift2);
    hipLaunchKernelGGL(gram3_mfma_kernel, dim3(512), dim3(256), 0, stream,
                       y2, scale2, shift2, G3, s3);
    hipLaunchKernelGGL(finalize3_kernel, dim3(2), dim3(64), 0, stream,
                       G3, s3, w2, b2, gamma2, beta2, scale3, shift3);
    hipLaunchKernelGGL(conv3_mfma_kernel, dim3(8192), dim3(256), 0, stream,
                       y2, w2bf, b2, scale2, shift2, scale3, shift3, out1);
}